// Round 5
// baseline (1094.076 us; speedup 1.0000x reference)
//
#include <hip/hip_runtime.h>

#define H 128
#define NODE_DIM 64
#define EDGE_DIM 32
#define KPRE (2*H + EDGE_DIM)   // 288
#define KPOST (13*H)            // 1664
#define T_OUT 256
#define L_DEPTH 5
#define POST_FRAGS (52*8*64)    // fragment-chunks per layer (posttrans W)
#define Y_FRAGS (4*16*64)       // fragment-chunks per layer (ygemm W)
#define WEFT_SZ (H*EDGE_DIM)    // 4096 floats per layer

typedef short short8v __attribute__((ext_vector_type(8)));
typedef float float4v __attribute__((ext_vector_type(4)));

__device__ __forceinline__ unsigned short f2bf(float x) {
    unsigned int b = __float_as_uint(x);
    return (unsigned short)((b + 0x7fffu + ((b >> 16) & 1u)) >> 16);  // RNE
}
__device__ __forceinline__ float bf2f(unsigned short u) {
    return __uint_as_float((unsigned int)u << 16);
}

// ---------------- input MLP: h = relu(node_feat @ W_in + b_in) ----------------
__global__ void k_input_mlp(const float* __restrict__ nf, const float* __restrict__ W,
                            const float* __restrict__ b, float* __restrict__ h, int N) {
    int gid = blockIdx.x * blockDim.x + threadIdx.x;
    int n = gid >> 7, c = gid & 127;
    if (n >= N) return;
    const float* nrow = nf + (size_t)n * NODE_DIM;
    float acc = 0.f;
#pragma unroll 8
    for (int k = 0; k < NODE_DIM; ++k)
        acc += nrow[k] * W[k * H + c];
    acc += b[c];
    h[(size_t)n * H + c] = fmaxf(acc, 0.f);
}

// ---------------- edge sort by dst: histogram, scan, scatter ----------------
__global__ void k_hist(const int* __restrict__ dst, int* __restrict__ deg_i, int E) {
    int e = blockIdx.x * blockDim.x + threadIdx.x;
    if (e < E) atomicAdd(&deg_i[dst[e]], 1);
}

__global__ __launch_bounds__(1024) void k_scan(const int* __restrict__ deg_i,
                                               int* __restrict__ row_start,
                                               int* __restrict__ cursor, int N) {
    __shared__ int part[1024];
    int t = threadIdx.x;
    int per = (N + 1023) / 1024;
    int base = t * per;
    int s = 0;
    for (int i = 0; i < per; ++i) {
        int idx = base + i;
        if (idx < N) s += deg_i[idx];
    }
    part[t] = s;
    __syncthreads();
    for (int off = 1; off < 1024; off <<= 1) {
        int v = (t >= off) ? part[t - off] : 0;
        __syncthreads();
        part[t] += v;
        __syncthreads();
    }
    int run = (t == 0) ? 0 : part[t - 1];
    for (int i = 0; i < per; ++i) {
        int idx = base + i;
        if (idx < N) {
            row_start[idx] = run;
            cursor[idx] = run;
            run += deg_i[idx];
        }
    }
    if (t == 1023) row_start[N] = run;
}

__global__ void k_sortscatter(const int* __restrict__ src, const int* __restrict__ dst,
                              int* __restrict__ cursor, int2* __restrict__ es, int E) {
    int e = blockIdx.x * blockDim.x + threadIdx.x;
    if (e >= E) return;
    int pos = atomicAdd(&cursor[dst[e]], 1);
    es[pos] = make_int2(src[e], e);
}

// ---------------- degree scalers ----------------
__global__ void k_scalers(const int* __restrict__ deg_i, float* __restrict__ invd,
                          float* __restrict__ amp, float* __restrict__ att, int N) {
    int n = blockIdx.x * blockDim.x + threadIdx.x;
    if (n >= N) return;
    float d = (float)deg_i[n];
    invd[n] = (d > 0.f) ? (1.f / d) : 0.f;
    float ld = logf(d + 1.f);
    amp[n] = ld;                                 // DELTA == 1.0
    att[n] = (d > 0.f) ? (1.f / ld) : 1.f;
}

// ------- weight conversion, ALL layers at once (weights static per call) -------
__global__ void k_wconv_all(const float* __restrict__ pre_W,
                            const float* __restrict__ post_W,
                            short* __restrict__ wf_y_all,
                            short* __restrict__ wf_post_all,
                            float* __restrict__ wefT_all) {
    int t = blockIdx.x * 256 + threadIdx.x;
    if (t < L_DEPTH * POST_FRAGS) {
        int l = t / POST_FRAGS, tt = t - l * POST_FRAGS;
        const float* qW = post_W + (size_t)l * KPOST * H;
        int lane = tt & 63, fc = tt >> 6;
        int kglob = fc >> 3, cb = fc & 7;
        int col = cb * 16 + (lane & 15);
        int k0 = kglob * 32 + ((lane >> 4) << 3);
        short8v o;
#pragma unroll
        for (int j = 0; j < 8; ++j)
            o[j] = (short)f2bf(qW[(size_t)(k0 + j) * H + col]);
        *(short8v*)(wf_post_all + (size_t)t * 8) = o;
        return;
    }
    t -= L_DEPTH * POST_FRAGS;
    if (t < L_DEPTH * Y_FRAGS) {
        int l = t / Y_FRAGS, tt = t - l * Y_FRAGS;
        const float* pW = pre_W + (size_t)l * KPRE * H;
        int lane = tt & 63, fc = tt >> 6;
        int kglob = fc >> 4, cb = fc & 15;
        int col = cb * 16 + (lane & 15);          // 0..255
        int k0 = kglob * 32 + ((lane >> 4) << 3); // 0..127
        int rowoff = (col < 128) ? 0 : 128;
        int c = col & 127;
        short8v o;
#pragma unroll
        for (int j = 0; j < 8; ++j)
            o[j] = (short)f2bf(pW[(size_t)(rowoff + k0 + j) * H + c]);
        *(short8v*)(wf_y_all + (size_t)t * 8) = o;
        return;
    }
    t -= L_DEPTH * Y_FRAGS;
    if (t >= L_DEPTH * WEFT_SZ) return;
    // WefT[l][c][k] = pre_W[l][(2H+k)*H + c]
    int l = t / WEFT_SZ, i = t - l * WEFT_SZ;
    int c = i >> 5, k = i & 31;
    wefT_all[t] = pre_W[(size_t)l * KPRE * H + (size_t)(2 * H + k) * H + c];
}

// ---------------- Y1(bf16) = h@W_src, Y2(f32) = h@W_dst via MFMA ----------------
__global__ __launch_bounds__(256) void k_ygemm_mfma(
    const float* __restrict__ h, const short* __restrict__ Wf,
    unsigned short* __restrict__ Y1bf, float* __restrict__ Y2, int N)
{
    __shared__ __align__(16) short Xs[64 * 128];   // 16 KB, XOR-swizzled
    int tid = threadIdx.x;
    int n0 = blockIdx.x * 64;
    int lane = tid & 63, wave = tid >> 6;
    float4v acc[16];
#pragma unroll
    for (int cb = 0; cb < 16; ++cb) acc[cb] = (float4v){0.f, 0.f, 0.f, 0.f};

    int rs = tid >> 4, c0 = (tid & 15) * 8;
#pragma unroll
    for (int j = 0; j < 4; ++j) {
        int r = rs + j * 16;
        int n = n0 + r;
        float4 v0 = {}, v1 = {};
        if (n < N) {
            const float* p = h + (size_t)n * H + c0;
            v0 = *(const float4*)p;
            v1 = *(const float4*)(p + 4);
        }
        short8v o;
        o[0] = (short)f2bf(v0.x); o[1] = (short)f2bf(v0.y);
        o[2] = (short)f2bf(v0.z); o[3] = (short)f2bf(v0.w);
        o[4] = (short)f2bf(v1.x); o[5] = (short)f2bf(v1.y);
        o[6] = (short)f2bf(v1.z); o[7] = (short)f2bf(v1.w);
        *(short8v*)((char*)Xs + r * 256 + ((c0 * 2) ^ ((r & 7) << 4))) = o;
    }
    __syncthreads();
    int rloc = wave * 16 + (lane & 15);
    int swz = (rloc & 7) << 4;
#pragma unroll
    for (int ks = 0; ks < 4; ++ks) {
        int boff = rloc * 256 + (((ks * 64) + ((lane >> 4) << 4)) ^ swz);
        short8v a = *(short8v*)((char*)Xs + boff);
        const short* wp = Wf + ((size_t)(ks * 16) * 64 + lane) * 8;
#pragma unroll
        for (int cb = 0; cb < 16; ++cb) {
            short8v b = *(const short8v*)(wp + (size_t)cb * 512);
            acc[cb] = __builtin_amdgcn_mfma_f32_16x16x32_bf16(a, b, acc[cb], 0, 0, 0);
        }
    }
    int col0 = lane & 15;
    int row0 = wave * 16 + ((lane >> 4) << 2);
#pragma unroll
    for (int cb = 0; cb < 16; ++cb) {
        int col = cb * 16 + col0;
#pragma unroll
        for (int r = 0; r < 4; ++r) {
            int n = n0 + row0 + r;
            if (n < N) {
                if (col < 128) Y1bf[(size_t)n * H + col] = f2bf(acc[cb][r]);
                else           Y2[(size_t)n * H + (col - 128)] = acc[cb][r];
            }
        }
    }
}

// ------- aggregation: for each node, reduce relu(Y1[src]+Y2[n]+ef@Wef+pb) -----
// WefT[c][k] held in 8 float4 VGPRs/thread; ef rows via scalar pipe (uniform
// address); 4 independent FMA chains per edge.
__global__ __launch_bounds__(128) void k_edge_agg(
    const unsigned short* __restrict__ Y1bf, const float* __restrict__ Y2,
    const float* __restrict__ ef, const float* __restrict__ WefT,
    const float* __restrict__ pb,
    const int2* __restrict__ es, const int* __restrict__ row_start,
    float* __restrict__ s_out, float* __restrict__ mx_out,
    float* __restrict__ mn_out, int N)
{
    int n = blockIdx.x;
    int c = threadIdx.x;   // 0..127 channel
    float4 wr[8];
#pragma unroll
    for (int j = 0; j < 8; ++j)
        wr[j] = *(const float4*)&WefT[c * EDGE_DIM + j * 4];
    int start = row_start[n], end = row_start[n + 1];
    float y2c = Y2[(size_t)n * H + c] + pb[c];
    bool any = end > start;
    float acc_s = 0.f;
    float acc_mx = any ? -3.4e38f : 0.f;
    float acc_mn = any ? 3.4e38f : 0.f;
#pragma unroll 2
    for (int p = start; p < end; ++p) {
        int2 se = es[p];
        int sn  = __builtin_amdgcn_readfirstlane(se.x);
        int eid = __builtin_amdgcn_readfirstlane(se.y);
        const float* efp = ef + (size_t)eid * EDGE_DIM;
        float a0 = bf2f(Y1bf[(size_t)sn * H + c]) + y2c;
        float a1 = 0.f, a2 = 0.f, a3 = 0.f;
#pragma unroll
        for (int kk = 0; kk < 8; ++kk) {
            a0 = fmaf(efp[kk],      ((const float*)&wr[kk >> 2])[kk & 3],             a0);
            a1 = fmaf(efp[kk + 8],  ((const float*)&wr[(kk + 8) >> 2])[kk & 3],       a1);
            a2 = fmaf(efp[kk + 16], ((const float*)&wr[(kk + 16) >> 2])[kk & 3],      a2);
            a3 = fmaf(efp[kk + 24], ((const float*)&wr[(kk + 24) >> 2])[kk & 3],      a3);
        }
        float m = fmaxf((a0 + a1) + (a2 + a3), 0.f);
        acc_s += m;
        acc_mx = fmaxf(acc_mx, m);
        acc_mn = fminf(acc_mn, m);
    }
    size_t o = (size_t)n * H + c;
    s_out[o] = acc_s;
    mx_out[o] = acc_mx;
    mn_out[o] = acc_mn;
}

// ---------------- posttrans via MFMA: h += relu(X @ qW + qb) ----------------
__global__ __launch_bounds__(128) void k_post_mfma(
    float* __restrict__ h,
    const float* __restrict__ s_in, const float* __restrict__ mx_in,
    const float* __restrict__ mn_in,
    const float* __restrict__ invd, const float* __restrict__ amp,
    const float* __restrict__ att,
    const short* __restrict__ Wf, const float* __restrict__ qb, int N)
{
    __shared__ __align__(16) short Xs[32 * 128];   // 8 KB, XOR-swizzled
    __shared__ float scal[3][32];
    int tid = threadIdx.x;
    int n0 = blockIdx.x * 32;
    int lane = tid & 63, wave = tid >> 6;

    if (tid < 96) {
        int which = tid >> 5, r = tid & 31;
        int n = n0 + r;
        const float* sp = (which == 0) ? invd : (which == 1 ? amp : att);
        scal[which][r] = (n < N) ? sp[n] : 0.f;
    }

    float4v acc[8];
#pragma unroll
    for (int cb = 0; cb < 8; ++cb) acc[cb] = (float4v){0.f, 0.f, 0.f, 0.f};

    int rs = tid >> 4;           // staging row base 0..7
    int c0 = (tid & 15) * 8;     // staging col base (floats)

    for (int kb = 0; kb < 13; ++kb) {
        const float* srcp;
        int comp = 0, grp = 0;
        if (kb == 0) {
            srcp = h;
        } else {
            comp = (kb - 1) & 3;          // 0 mean, 1 max, 2 min, 3 sum
            grp  = (kb - 1) >> 2;         // 0: x1, 1: x amp, 2: x att
            srcp = (comp == 1) ? mx_in : (comp == 2 ? mn_in : s_in);
        }
#pragma unroll
        for (int j = 0; j < 4; ++j) {
            int r = rs + j * 8;
            int n = n0 + r;
            float4 v0 = {}, v1 = {};
            if (n < N) {
                const float* p = srcp + (size_t)n * H + c0;
                v0 = *(const float4*)p;
                v1 = *(const float4*)(p + 4);
            }
            float f = 1.f;
            if (kb != 0) {
                f = (grp == 0) ? 1.f : scal[grp][r];
                if (comp == 0) f *= scal[0][r];
            }
            short8v o;
            o[0] = (short)f2bf(v0.x * f); o[1] = (short)f2bf(v0.y * f);
            o[2] = (short)f2bf(v0.z * f); o[3] = (short)f2bf(v0.w * f);
            o[4] = (short)f2bf(v1.x * f); o[5] = (short)f2bf(v1.y * f);
            o[6] = (short)f2bf(v1.z * f); o[7] = (short)f2bf(v1.w * f);
            *(short8v*)((char*)Xs + r * 256 + ((c0 * 2) ^ ((r & 7) << 4))) = o;
        }
        __syncthreads();
        int rloc = wave * 16 + (lane & 15);   // 0..31
        int swz = (rloc & 7) << 4;
#pragma unroll
        for (int ks = 0; ks < 4; ++ks) {
            int boff = rloc * 256 + (((ks * 64) + ((lane >> 4) << 4)) ^ swz);
            short8v a = *(short8v*)((char*)Xs + boff);
            const short* wp = Wf + ((size_t)((kb * 4 + ks) * 8) * 64 + lane) * 8;
#pragma unroll
            for (int cb = 0; cb < 8; ++cb) {
                short8v b = *(const short8v*)(wp + (size_t)cb * 512);
                acc[cb] = __builtin_amdgcn_mfma_f32_16x16x32_bf16(a, b, acc[cb], 0, 0, 0);
            }
        }
        __syncthreads();
    }
    int col0 = lane & 15;
    int row0 = wave * 16 + ((lane >> 4) << 2);  // 0..31
#pragma unroll
    for (int cb = 0; cb < 8; ++cb) {
        int col = cb * 16 + col0;
        float bb = qb[col];
#pragma unroll
        for (int r = 0; r < 4; ++r) {
            int n = n0 + row0 + r;
            if (n < N)
                h[(size_t)n * H + col] += fmaxf(acc[cb][r] + bb, 0.f);
        }
    }
}

// ---------------- graph readout scatter ----------------
__global__ void k_readout_scatter(const float* __restrict__ h, const int* __restrict__ n2g,
                                  float* __restrict__ g_sum, unsigned int* __restrict__ g_max,
                                  int N) {
    int gid = blockIdx.x * blockDim.x + threadIdx.x;
    int n = gid >> 7, c = gid & 127;
    if (n >= N) return;
    int g = n2g[n];
    float v = h[(size_t)n * H + c];
    atomicAdd(&g_sum[(size_t)g * H + c], v);
    atomicMax(&g_max[(size_t)g * H + c], __float_as_uint(v));  // h >= 0 always
}

__global__ void k_gcnt(const int* __restrict__ n2g, float* __restrict__ g_cnt, int N) {
    int n = blockIdx.x * blockDim.x + threadIdx.x;
    if (n < N) atomicAdd(&g_cnt[n2g[n]], 1.f);
}

// ---------------- final MLP ----------------
__global__ __launch_bounds__(256) void k_final(
    const float* __restrict__ g_sum, const float* __restrict__ g_max,
    const float* __restrict__ g_cnt,
    const float* __restrict__ W1, const float* __restrict__ b1,
    const float* __restrict__ W2, const float* __restrict__ b2,
    float* __restrict__ out)
{
    __shared__ float hid[H];
    int b = blockIdx.x, t = threadIdx.x;
    float cnt = g_cnt[b];
    if (t < H) {
        float acc = 0.f;
        float rc = 1.f / fmaxf(cnt, 1.f);
        for (int k = 0; k < 3 * H; ++k) {
            float x;
            if (k < H)          x = g_sum[(size_t)b * H + k] * rc;
            else if (k < 2 * H) x = (cnt > 0.f) ? g_max[(size_t)b * H + (k - H)] : 0.f;
            else                x = g_sum[(size_t)b * H + (k - 2 * H)];
            acc += x * W1[k * H + t];
        }
        hid[t] = fmaxf(acc + b1[t], 0.f);
    }
    __syncthreads();
    float acc = 0.f;
#pragma unroll 8
    for (int k = 0; k < H; ++k)
        acc += hid[k] * W2[k * T_OUT + t];
    out[(size_t)b * T_OUT + t] = acc + b2[t];
}

extern "C" void kernel_launch(void* const* d_in, const int* in_sizes, int n_in,
                              void* d_out, int out_size, void* d_ws, size_t ws_size,
                              hipStream_t stream) {
    const float* node_feat = (const float*)d_in[0];
    const float* edge_feat = (const float*)d_in[1];
    const float* W_in  = (const float*)d_in[2];
    const float* b_in  = (const float*)d_in[3];
    const float* pre_W = (const float*)d_in[4];
    const float* pre_b = (const float*)d_in[5];
    const float* post_W = (const float*)d_in[6];
    const float* post_b = (const float*)d_in[7];
    const float* out_W1 = (const float*)d_in[8];
    const float* out_b1 = (const float*)d_in[9];
    const float* out_W2 = (const float*)d_in[10];
    const float* out_b2 = (const float*)d_in[11];
    const int* src = (const int*)d_in[12];
    const int* dst = (const int*)d_in[13];
    const int* n2g = (const int*)d_in[14];

    int N = in_sizes[0] / NODE_DIM;
    int E = in_sizes[1] / EDGE_DIM;
    int B = out_size / T_OUT;
    float* out = (float*)d_out;

    float* ws = (float*)d_ws;
    float* h      = ws; ws += (size_t)N * H;
    float* s_buf  = ws; ws += (size_t)N * H;
    float* mx     = ws; ws += (size_t)N * H;
    float* mn     = ws; ws += (size_t)N * H;
    unsigned short* Y1bf = (unsigned short*)ws; ws += (size_t)N * H / 2;
    float* Y2     = ws; ws += (size_t)N * H;
    float* invd = ws; ws += N;
    float* amp  = ws; ws += N;
    float* att  = ws; ws += N;
    float* g_sum = ws; ws += (size_t)B * H;
    unsigned int* g_max = (unsigned int*)ws; ws += (size_t)B * H;
    float* g_cnt = ws; ws += B;
    int* deg_i     = (int*)ws; ws += N;
    int* row_start = (int*)ws; ws += N + 1;
    int* cursor    = (int*)ws; ws += N + 1;   // keep int2 array 8B-aligned
    int2* es       = (int2*)ws; ws += 2 * (size_t)E;
    short* wf_post_all = (short*)ws; ws += (size_t)L_DEPTH * POST_FRAGS * 8 / 2;
    short* wf_y_all    = (short*)ws; ws += (size_t)L_DEPTH * Y_FRAGS * 8 / 2;
    float* wefT_all    = ws; ws += (size_t)L_DEPTH * WEFT_SZ;

    // input MLP
    k_input_mlp<<<((size_t)N * H + 255) / 256, 256, 0, stream>>>(node_feat, W_in, b_in, h, N);

    // edge sort by dst (dst static across layers)
    hipMemsetAsync(deg_i, 0, (size_t)N * sizeof(int), stream);
    k_hist<<<(E + 255) / 256, 256, 0, stream>>>(dst, deg_i, E);
    k_scan<<<1, 1024, 0, stream>>>(deg_i, row_start, cursor, N);
    k_sortscatter<<<(E + 255) / 256, 256, 0, stream>>>(src, dst, cursor, es, E);
    k_scalers<<<(N + 255) / 256, 256, 0, stream>>>(deg_i, invd, amp, att, N);

    // all-layer weight conversion (once)
    {
        int tot = L_DEPTH * (POST_FRAGS + Y_FRAGS + WEFT_SZ);
        k_wconv_all<<<(tot + 255) / 256, 256, 0, stream>>>(pre_W, post_W, wf_y_all,
                                                           wf_post_all, wefT_all);
    }

    for (int l = 0; l < L_DEPTH; ++l) {
        k_ygemm_mfma<<<(N + 63) / 64, 256, 0, stream>>>(
            h, wf_y_all + (size_t)l * Y_FRAGS * 8, Y1bf, Y2, N);
        k_edge_agg<<<N, 128, 0, stream>>>(
            Y1bf, Y2, edge_feat, wefT_all + (size_t)l * WEFT_SZ, pre_b + (size_t)l * H,
            es, row_start, s_buf, mx, mn, N);
        k_post_mfma<<<(N + 31) / 32, 128, 0, stream>>>(
            h, s_buf, mx, mn, invd, amp, att,
            wf_post_all + (size_t)l * POST_FRAGS * 8, post_b + (size_t)l * H, N);
    }

    // readout
    hipMemsetAsync(g_sum, 0, (size_t)B * H * sizeof(float), stream);
    hipMemsetAsync(g_max, 0, (size_t)B * H * sizeof(float), stream);
    hipMemsetAsync(g_cnt, 0, (size_t)B * sizeof(float), stream);
    k_readout_scatter<<<((size_t)N * H + 255) / 256, 256, 0, stream>>>(h, n2g, g_sum, g_max, N);
    k_gcnt<<<(N + 255) / 256, 256, 0, stream>>>(n2g, g_cnt, N);
    k_final<<<B, 256, 0, stream>>>(g_sum, (const float*)g_max, g_cnt,
                                   out_W1, out_b1, out_W2, out_b2, out);
}